// Round 9
// baseline (249.986 us; speedup 1.0000x reference)
//
#include <hip/hip_runtime.h>

// Problem constants: N=4 vars, B=4, T=512, D=512, H=8, DK=DV=64
// NBH = N*B*H = 128 (n,b,h) combos; M = N*B*T = 8192 rows.
// All global I/O is FP32 (per reference). Compute path converts to bf16 for MFMA.

typedef __bf16 bf16x8 __attribute__((ext_vector_type(8)));
typedef short shortx4 __attribute__((ext_vector_type(4)));
typedef float floatx4 __attribute__((ext_vector_type(4)));
typedef float floatx16 __attribute__((ext_vector_type(16)));
typedef unsigned short ushortx8 __attribute__((ext_vector_type(8)));

static __device__ __forceinline__ unsigned short f2bf(float f) {
  union { __bf16 h; unsigned short u; } c; c.h = (__bf16)f; return c.u;
}
static __device__ __forceinline__ float bf2f(unsigned short u) {
  union { unsigned u32; float f; } c; c.u32 = ((unsigned)u) << 16; return c.f;
}

// 16B global->LDS DMA; LDS dest = lp + lane*16 (wave-uniform base).
static __device__ __forceinline__ void gload16(const unsigned short* gp, unsigned short* lp) {
  __builtin_amdgcn_global_load_lds(
      (const __attribute__((address_space(1))) unsigned int*)gp,
      (__attribute__((address_space(3))) unsigned int*)lp, 16, 0, 0);
}

// exp folded constants: Q pre-scaled by 0.125*log2(e); S^T acc C-init = -12*log2(e)
#define QSCALE 0.18033688011112042f
#define SHIFT2 (-17.312340489609306f)

// ---------------------------------------------------------------------------
// prep: blocks 0..255 transpose+convert the 4 weights (T[n][k] = bf16 W[k][n]);
// blocks 256..2303 convert x fp32 -> bf16 (8 elems/thread).
// ---------------------------------------------------------------------------
__global__ __launch_bounds__(256) void prep(
    const float* __restrict__ Wq, const float* __restrict__ Wk,
    const float* __restrict__ Wv, const float* __restrict__ Wo,
    const float* __restrict__ x,
    unsigned short* __restrict__ wqkvT, unsigned short* __restrict__ woT,
    unsigned short* __restrict__ x_bf)
{
  const int bid = blockIdx.x;
  const int tid = threadIdx.x;
  if (bid < 256) {
    __shared__ unsigned short lds[64][65];
    const int z = bid >> 6, rest = bid & 63;
    const int k0 = (rest >> 3) * 64, n0 = (rest & 7) * 64;
    const float* W; unsigned short* T;
    if (z == 0)      { W = Wq; T = wqkvT; }
    else if (z == 1) { W = Wk; T = wqkvT + 262144; }
    else if (z == 2) { W = Wv; T = wqkvT + 524288; }
    else             { W = Wo; T = woT; }
    const int xx = tid & 63, yy = tid >> 6;
#pragma unroll
    for (int i = 0; i < 16; ++i) {
      const int row = yy * 16 + i;
      lds[row][xx] = f2bf(W[(size_t)(k0 + row) * 512 + n0 + xx]);
    }
    __syncthreads();
#pragma unroll
    for (int i = 0; i < 16; ++i) {
      const int nr = yy * 16 + i;
      T[(size_t)(n0 + nr) * 512 + k0 + xx] = lds[xx][nr];
    }
  } else {
    const int i = (bid - 256) * 256 + tid;
    const float4 a = ((const float4*)x)[i * 2];
    const float4 b = ((const float4*)x)[i * 2 + 1];
    ushortx8 o;
    o[0] = f2bf(a.x); o[1] = f2bf(a.y); o[2] = f2bf(a.z); o[3] = f2bf(a.w);
    o[4] = f2bf(b.x); o[5] = f2bf(b.y); o[6] = f2bf(b.z); o[7] = f2bf(b.w);
    *(ushortx8*)(x_bf + (size_t)i * 8) = o;
  }
}

// ---------------------------------------------------------------------------
// 128x128-tile bf16 GEMM for QKV projection. A = x_bf, B = wqkvT [1536][512].
// grid (64, 12); by selects output: 0-3 Q, 4-7 K, 8-11 V.
// ---------------------------------------------------------------------------
__global__ __launch_bounds__(256) void gemm_qkv(
    const unsigned short* __restrict__ Xb,
    const unsigned short* __restrict__ BT,
    const float* __restrict__ bq, const float* __restrict__ bk,
    const float* __restrict__ bv,
    unsigned short* __restrict__ Qo, unsigned short* __restrict__ Ko,
    unsigned short* __restrict__ Vo)
{
  __shared__ __align__(16) unsigned short lA[128][72];
  __shared__ __align__(16) unsigned short lB[128][72];
  const int tid  = threadIdx.x;
  const int wv   = tid >> 6, lane = tid & 63;
  const int quad = lane >> 4, l16 = lane & 15;
  const int wm = wv >> 1, wn = wv & 1;
  const int m0  = blockIdx.x * 128;
  const int n0g = blockIdx.y * 128;
  const int sel = n0g >> 9;                      // 0=Q,1=K,2=V
  const float* bias = (sel == 0) ? bq : (sel == 1) ? bk : bv;
  const float scale = (sel == 0) ? QSCALE : 1.0f;
  unsigned short* outp = (sel == 0) ? Qo : (sel == 1) ? Ko : Vo;

  floatx4 acc[4][4] = {};
  const int srow = tid >> 1, sc0 = (tid & 1) * 32;

  for (int kc = 0; kc < 512; kc += 64) {
    __syncthreads();
    const unsigned short* as = Xb + (size_t)(m0 + srow) * 512 + kc + sc0;
    const unsigned short* bs = BT + (size_t)(n0g + srow) * 512 + kc + sc0;
#pragma unroll
    for (int j = 0; j < 4; ++j) {
      *(bf16x8*)&lA[srow][sc0 + j * 8] = *(const bf16x8*)(as + j * 8);
      *(bf16x8*)&lB[srow][sc0 + j * 8] = *(const bf16x8*)(bs + j * 8);
    }
    __syncthreads();
    bf16x8 af[4][2];
#pragma unroll
    for (int ti = 0; ti < 4; ++ti) {
      af[ti][0] = *(const bf16x8*)&lA[wm * 64 + ti * 16 + l16][quad * 8];
      af[ti][1] = *(const bf16x8*)&lA[wm * 64 + ti * 16 + l16][32 + quad * 8];
    }
#pragma unroll
    for (int ni = 0; ni < 4; ++ni) {
      bf16x8 b0 = *(const bf16x8*)&lB[wn * 64 + ni * 16 + l16][quad * 8];
      bf16x8 b1 = *(const bf16x8*)&lB[wn * 64 + ni * 16 + l16][32 + quad * 8];
#pragma unroll
      for (int ti = 0; ti < 4; ++ti) {
        acc[ti][ni] = __builtin_amdgcn_mfma_f32_16x16x32_bf16(af[ti][0], b0, acc[ti][ni], 0, 0, 0);
        acc[ti][ni] = __builtin_amdgcn_mfma_f32_16x16x32_bf16(af[ti][1], b1, acc[ti][ni], 0, 0, 0);
      }
    }
  }

#pragma unroll
  for (int ni = 0; ni < 4; ++ni) {
    const int n = (n0g & 511) + wn * 64 + ni * 16 + l16;
    const float bvv = bias[n];
    const int hh = n >> 6, dk = n & 63;
#pragma unroll
    for (int ti = 0; ti < 4; ++ti) {
      const int mb = m0 + wm * 64 + ti * 16 + quad * 4;
#pragma unroll
      for (int r = 0; r < 4; ++r) {
        const int m = mb + r;
        const int nb = m >> 9, t = m & 511;
        const float v = (acc[ti][ni][r] + bvv) * scale;
        if (sel == 2)
          outp[((size_t)(nb * 8 + hh) * 64 + dk) * 512 + t] = f2bf(v);
        else
          outp[((size_t)(nb * 8 + hh) * 512 + t) * 64 + dk] = f2bf(v);
      }
    }
  }
}

// ---------------------------------------------------------------------------
// 128x128-tile output projection with fused c-group reduce:
// A = ctx2[0] + ctx2[1] (added during staging), B = woT; tmp fp32 [8192][512].
// ---------------------------------------------------------------------------
__global__ __launch_bounds__(256) void gemm_out(
    const unsigned short* __restrict__ C0, const unsigned short* __restrict__ C1,
    const unsigned short* __restrict__ BT, float* __restrict__ Cout)
{
  __shared__ __align__(16) unsigned short lA[128][72];
  __shared__ __align__(16) unsigned short lB[128][72];
  const int tid  = threadIdx.x;
  const int wv   = tid >> 6, lane = tid & 63;
  const int quad = lane >> 4, l16 = lane & 15;
  const int wm = wv >> 1, wn = wv & 1;
  const int m0 = blockIdx.x * 128, n0 = blockIdx.y * 128;

  floatx4 acc[4][4] = {};
  const int srow = tid >> 1, sc0 = (tid & 1) * 32;

  for (int kc = 0; kc < 512; kc += 64) {
    __syncthreads();
    const size_t aoff = (size_t)(m0 + srow) * 512 + kc + sc0;
    const unsigned short* bs = BT + (size_t)(n0 + srow) * 512 + kc + sc0;
#pragma unroll
    for (int j = 0; j < 4; ++j) {
      ushortx8 a0 = *(const ushortx8*)(C0 + aoff + j * 8);
      ushortx8 a1 = *(const ushortx8*)(C1 + aoff + j * 8);
      ushortx8 o;
#pragma unroll
      for (int e = 0; e < 8; ++e) o[e] = f2bf(bf2f(a0[e]) + bf2f(a1[e]));
      *(ushortx8*)&lA[srow][sc0 + j * 8] = o;
      *(bf16x8*)&lB[srow][sc0 + j * 8] = *(const bf16x8*)(bs + j * 8);
    }
    __syncthreads();
    bf16x8 af[4][2];
#pragma unroll
    for (int ti = 0; ti < 4; ++ti) {
      af[ti][0] = *(const bf16x8*)&lA[wm * 64 + ti * 16 + l16][quad * 8];
      af[ti][1] = *(const bf16x8*)&lA[wm * 64 + ti * 16 + l16][32 + quad * 8];
    }
#pragma unroll
    for (int ni = 0; ni < 4; ++ni) {
      bf16x8 b0 = *(const bf16x8*)&lB[wn * 64 + ni * 16 + l16][quad * 8];
      bf16x8 b1 = *(const bf16x8*)&lB[wn * 64 + ni * 16 + l16][32 + quad * 8];
#pragma unroll
      for (int ti = 0; ti < 4; ++ti) {
        acc[ti][ni] = __builtin_amdgcn_mfma_f32_16x16x32_bf16(af[ti][0], b0, acc[ti][ni], 0, 0, 0);
        acc[ti][ni] = __builtin_amdgcn_mfma_f32_16x16x32_bf16(af[ti][1], b1, acc[ti][ni], 0, 0, 0);
      }
    }
  }

#pragma unroll
  for (int ni = 0; ni < 4; ++ni) {
    const int n = n0 + wn * 64 + ni * 16 + l16;
#pragma unroll
    for (int ti = 0; ti < 4; ++ti) {
      const int mb = m0 + wm * 64 + ti * 16 + quad * 4;
#pragma unroll
      for (int r = 0; r < 4; ++r)
        Cout[(size_t)(mb + r) * 512 + n] = acc[ti][ni][r];
    }
  }
}

// ---------------------------------------------------------------------------
// Flash attention v6: 2 key-vars per block (grid 1024), plane read-modify-
// write instead of an ofin register accumulator; K/V staged via
// global_load_lds (16B DMA) into XOR-swizzled unpadded LDS (stride 64:
// logical 16B group g of row r lives at phys group g^(r&7)); no prefetch
// registers. __launch_bounds__(256,4) pins <=128 regs -> 4 waves/SIMD.
// S^T = K·Q^T (32x32x16, C-init SHIFT2, Q pre-scaled QSCALE) -> P=exp2(sacc)
// -> PV via 32x32x8 with P straight from the accumulator.
// ---------------------------------------------------------------------------
__global__ __launch_bounds__(256, 4) void flash_kernel(
    const unsigned short* __restrict__ Q,    // [128][512][64] (pre-scaled)
    const unsigned short* __restrict__ K,    // [128][512][64]
    const unsigned short* __restrict__ VT,   // [128][64][512]
    unsigned short* __restrict__ CTX2)       // [2][8192][512]
{
  __shared__ __align__(16) unsigned short lK[2][64][64];   // [s][dk], swizzled
  __shared__ __align__(16) unsigned short lV[2][64][64];   // [dv][s], swizzled
  const int tid  = threadIdx.x;
  const int wv   = tid >> 6, lane = tid & 63;
  const int l32  = lane & 31, u = lane >> 5;

  // XCD swizzle: the 4 t-tiles of one (cg,nbh) share an XCD.
  const int lin  = blockIdx.x;                  // 0..1023
  const int xcd  = lin & 7, slot = lin >> 3;
  const int tile = slot & 3;
  const int nbh  = xcd * 16 + ((slot >> 2) & 15);
  const int cg   = slot >> 6;                   // key-var group 0..1
  const int t0   = tile * 128;
  const int h = nbh & 7, nb = nbh >> 3, b = nb & 3;

  // Q fragments: B-operand of 32x32x16 (n=l32=t, k=8u+j per 16-chunk).
  const unsigned short* qbase = Q + ((size_t)nbh * 512 + (t0 + wv * 32 + l32)) * 64;
  bf16x8 qf[4];
#pragma unroll
  for (int c16 = 0; c16 < 4; ++c16)
    qf[c16] = *(const bf16x8*)(qbase + c16 * 16 + u * 8);

  // DMA staging lane constants: instruction covers 8 rows (base r8 % 8 == 0),
  // lane's row = r8 + (lane>>3); logical group fetched = (lane&7)^(lane>>3)
  // so that phys group (lane&7) holds logical g^(r&7).
  const int lrow8 = lane >> 3;                  // 0..7
  const int glog  = (lane & 7) ^ lrow8;         // lane-constant
  const int m7    = l32 & 7;                    // read-side swizzle mask

  auto issue = [&](int it, int p) {
    const int c = cg * 2 + (it >> 3), s0 = (it & 7) * 64;
    const size_t kvbh = (size_t)((c * 4 + b) * 8 + h);
    const unsigned short* kb = K  + kvbh * (512 * 64) + (size_t)s0 * 64;
    const unsigned short* vb = VT + kvbh * (64 * 512) + s0;
#pragma unroll
    for (int j = 0; j < 2; ++j) {
      const int r8 = wv * 16 + j * 8;
      gload16(kb + (size_t)(r8 + lrow8) * 64  + glog * 8, &lK[p][r8][0]);
      gload16(vb + (size_t)(r8 + lrow8) * 512 + glog * 8, &lV[p][r8][0]);
    }
  };

  issue(0, 0);
  __syncthreads();                              // vmcnt drained -> buf0 ready

  floatx16 oc0 = {}, oc1 = {};
  float lacc = 0.f;

  for (int it = 0; it < 16; ++it) {
    const int cur = it & 1;
    const int st = it & 7;
    if (st == 0) { oc0 = floatx16{}; oc1 = floatx16{}; lacc = 0.f; }

    if (it < 15) issue(it + 1, cur ^ 1);        // DMA overlaps this compute

    // S^T = K·Q^T with C = SHIFT2 so P = 2^sacc directly.
    floatx16 sacc0, sacc1;
#pragma unroll
    for (int r = 0; r < 16; ++r) { sacc0[r] = SHIFT2; sacc1[r] = SHIFT2; }
#pragma unroll
    for (int c16 = 0; c16 < 4; ++c16) {
      const int pc = ((c16 * 2 + u) ^ m7) * 8;  // phys col of logical group
      bf16x8 ak0 = *(const bf16x8*)&lK[cur][l32][pc];
      bf16x8 ak1 = *(const bf16x8*)&lK[cur][32 + l32][pc];  // (32+l32)&7 == m7
      sacc0 = __builtin_amdgcn_mfma_f32_32x32x16_bf16(ak0, qf[c16], sacc0, 0, 0, 0);
      sacc1 = __builtin_amdgcn_mfma_f32_32x32x16_bf16(ak1, qf[c16], sacc1, 0, 0, 0);
    }

    // exp2 -> pack -> PV; regs [4c8..4c8+3] are the 32x32x8 A-operand.
#pragma unroll
    for (int sb = 0; sb < 2; ++sb) {
      const floatx16& sa = sb ? sacc1 : sacc0;
#pragma unroll
      for (int c8 = 0; c8 < 4; ++c8) {
        float e0 = __builtin_amdgcn_exp2f(sa[4 * c8 + 0]);
        float e1 = __builtin_amdgcn_exp2f(sa[4 * c8 + 1]);
        float e2 = __builtin_amdgcn_exp2f(sa[4 * c8 + 2]);
        float e3 = __builtin_amdgcn_exp2f(sa[4 * c8 + 3]);
        lacc += (e0 + e1) + (e2 + e3);
        shortx4 pf;
        pf[0] = (short)f2bf(e0); pf[1] = (short)f2bf(e1);
        pf[2] = (short)f2bf(e2); pf[3] = (short)f2bf(e3);
        const int pv = ((sb * 4 + c8) ^ m7) * 8 + u * 4;   // phys 8B position
        shortx4 vf0 = *(const shortx4*)&lV[cur][l32][pv];
        shortx4 vf1 = *(const shortx4*)&lV[cur][32 + l32][pv];
        oc0 = __builtin_amdgcn_mfma_f32_32x32x8bf16_1k(pf, vf0, oc0, 0, 0, 0);
        oc1 = __builtin_amdgcn_mfma_f32_32x32x8bf16_1k(pf, vf1, oc1, 0, 0, 0);
      }
    }

    if (st == 7) {   // finalize this key-var: normalize, store/accumulate plane
      float s = lacc;
      s += __shfl_xor(s, 32);
      const float inv = 1.0f / s;
      unsigned short* outp = CTX2 + (size_t)cg * (8192 * 512);
      const int mbase = nb * 512 + t0 + wv * 32;
      const int phase = it >> 3;                // 0: first c, 1: second c
#pragma unroll
      for (int r = 0; r < 16; ++r) {
        const int trow = (r & 3) + 8 * (r >> 2) + 4 * u;
        const float invr = __shfl(inv, trow);   // denominator of O-row t_r
        const size_t rowoff = (size_t)(mbase + trow) * 512 + h * 64;
        float v0 = oc0[r] * invr, v1 = oc1[r] * invr;
        if (phase == 1) {                       // same-thread RMW, no race
          v0 += bf2f(outp[rowoff + l32]);
          v1 += bf2f(outp[rowoff + 32 + l32]);
        }
        outp[rowoff + l32]      = f2bf(v0);
        outp[rowoff + 32 + l32] = f2bf(v1);
      }
    }
    __syncthreads();   // drains it+1 DMA; protects buf reuse
  }
}

// ---------------------------------------------------------------------------
// Residual + LayerNorm (fp32), one wave per row: no LDS, no barriers.
// ---------------------------------------------------------------------------
__global__ __launch_bounds__(256) void ln_kernel(
    const float* __restrict__ x, const float* __restrict__ tmp,
    const float* __restrict__ bo, const float* __restrict__ gamma,
    const float* __restrict__ beta, float* __restrict__ out)
{
  const int wv   = threadIdx.x >> 6, lane = threadIdx.x & 63;
  const int row  = blockIdx.x * 4 + wv;
  const int col  = lane * 8;
  const size_t base = (size_t)row * 512 + col;
  const float4 x0 = *(const float4*)(x + base);
  const float4 x1 = *(const float4*)(x + base + 4);
  const float4 t0 = *(const float4*)(tmp + base);
  const float4 t1 = *(const float4*)(tmp + base + 4);
  const float4 b0 = *(const float4*)(bo + col);
  const float4 b1 = *(const float4*)(bo + col + 4);
  float r[8];
  r[0] = x0.x + 0.25f * t0.x + b0.x;  r[1] = x0.y + 0.25f * t0.y + b0.y;
  r[2] = x0.z + 0.25f * t0.z + b0.z;  r[3] = x0.w + 0.25f * t0.w + b0.w;
  r[4] = x1.x + 0.25f * t1.x + b1.x;  r[5] = x1.y + 0.25f * t1.y + b1.y;
  r[6] = x1.z + 0.25f * t1.z + b1.z;  r[7] = x1.w + 0.25f * t1.w + b1.w;
  float s = 0.f, sq = 0.f;
#pragma unroll
  for (int j = 0; j < 8; ++j) { s += r[j]; sq += r[j] * r[j]; }
#pragma unroll
  for (int off = 1; off < 64; off <<= 1) {
    s  += __shfl_xor(s, off);
    sq += __shfl_xor(sq, off);
  }
  const float mu  = s * (1.0f / 512.0f);
  const float var = sq * (1.0f / 512.0f) - mu * mu;
  const float inv = rsqrtf(var + 1e-5f);
  const float4 g0 = *(const float4*)(gamma + col);
  const float4 g1 = *(const float4*)(gamma + col + 4);
  const float4 be0 = *(const float4*)(beta + col);
  const float4 be1 = *(const float4*)(beta + col + 4);
  float4 o0, o1;
  o0.x = (r[0] - mu) * inv * g0.x + be0.x;  o0.y = (r[1] - mu) * inv * g0.y + be0.y;
  o0.z = (r[2] - mu) * inv * g0.z + be0.z;  o0.w = (r[3] - mu) * inv * g0.w + be0.w;
  o1.x = (r[4] - mu) * inv * g1.x + be1.x;  o1.y = (r[5] - mu) * inv * g1.y + be1.y;
  o1.z = (r[6] - mu) * inv * g1.z + be1.z;  o1.w = (r[7] - mu) * inv * g1.w + be1.w;
  *(float4*)(out + base)     = o0;
  *(float4*)(out + base + 4) = o1;
}

// ---------------------------------------------------------------------------
extern "C" void kernel_launch(void* const* d_in, const int* in_sizes, int n_in,
                              void* d_out, int out_size, void* d_ws, size_t ws_size,
                              hipStream_t stream) {
  const float* x     = (const float*)d_in[0];
  const float* Wq    = (const float*)d_in[1];
  const float* bq    = (const float*)d_in[2];
  const float* Wk    = (const float*)d_in[3];
  const float* bk    = (const float*)d_in[4];
  const float* Wv    = (const float*)d_in[5];
  const float* bv    = (const float*)d_in[6];
  const float* Wo    = (const float*)d_in[7];
  const float* bo    = (const float*)d_in[8];
  const float* gamma = (const float*)d_in[9];
  const float* beta  = (const float*)d_in[10];
  float* out = (float*)d_out;

  // Workspace (42 MB):
  //   [0,  8M)  q_bf   (qkv->flash)          | tmp fp32 [0,16M) after flash
  //   [8, 16M)  k_bf   (qkv->flash)          |
  //   [16,24M)  vt_bf  (qkv->flash)
  //   [24,32M)  x_bf   (prep->qkv)           | ctx2[0] (flash->gemm_out)
  //   [32,40M)                                 ctx2[1]
  //   [40,41.5M) wqkvT [1536][512]; [41.5,42M) woT
  char* w = (char*)d_ws;
  unsigned short* q_bf  = (unsigned short*)(w);
  unsigned short* k_bf  = (unsigned short*)(w + (size_t)8  * 1024 * 1024);
  unsigned short* vt_bf = (unsigned short*)(w + (size_t)16 * 1024 * 1024);
  unsigned short* x_bf  = (unsigned short*)(w + (size_t)24 * 1024 * 1024);
  unsigned short* ctx2  = (unsigned short*)(w + (size_t)24 * 1024 * 1024);
  unsigned short* wqkvT = (unsigned short*)(w + (size_t)40 * 1024 * 1024);
  unsigned short* woT   = wqkvT + 786432;
  float* tmp            = (float*)(w);   // over q_bf/k_bf (dead post-flash)

  prep<<<2304, 256, 0, stream>>>(Wq, Wk, Wv, Wo, x, wqkvT, woT, x_bf);
  gemm_qkv<<<dim3(64, 12), 256, 0, stream>>>(x_bf, wqkvT, bq, bk, bv,
                                             q_bf, k_bf, vt_bf);
  flash_kernel<<<1024, 256, 0, stream>>>(q_bf, k_bf, vt_bf, ctx2);
  gemm_out<<<dim3(64, 4), 256, 0, stream>>>(ctx2, ctx2 + (size_t)8192 * 512,
                                            woT, tmp);
  ln_kernel<<<2048, 256, 0, stream>>>(x, tmp, bo, gamma, beta, out);
}

// Round 10
// 195.538 us; speedup vs baseline: 1.2785x; 1.2785x over previous
//
#include <hip/hip_runtime.h>

// Problem constants: N=4 vars, B=4, T=512, D=512, H=8, DK=DV=64
// NBH = N*B*H = 128 (n,b,h) combos; M = N*B*T = 8192 rows.
// All global I/O is FP32 (per reference). Compute path converts to bf16 for MFMA.

typedef __bf16 bf16x8 __attribute__((ext_vector_type(8)));
typedef __bf16 bf16x4 __attribute__((ext_vector_type(4)));
typedef short shortx4 __attribute__((ext_vector_type(4)));
typedef float floatx4 __attribute__((ext_vector_type(4)));
typedef float floatx16 __attribute__((ext_vector_type(16)));
typedef unsigned short ushortx8 __attribute__((ext_vector_type(8)));

static __device__ __forceinline__ unsigned short f2bf(float f) {
  union { __bf16 h; unsigned short u; } c; c.h = (__bf16)f; return c.u;
}
static __device__ __forceinline__ float bf2f(unsigned short u) {
  union { unsigned u32; float f; } c; c.u32 = ((unsigned)u) << 16; return c.f;
}

// exp folded constants: Q pre-scaled by 0.125*log2(e); S^T acc C-init = -12*log2(e)
#define QSCALE 0.18033688011112042f
#define SHIFT2 (-17.312340489609306f)

// ---------------------------------------------------------------------------
// prep: blocks 0..255 transpose+convert the 4 weights (T[n][k] = bf16 W[k][n]);
// blocks 256..2303 convert x fp32 -> bf16 (8 elems/thread).
// ---------------------------------------------------------------------------
__global__ __launch_bounds__(256) void prep(
    const float* __restrict__ Wq, const float* __restrict__ Wk,
    const float* __restrict__ Wv, const float* __restrict__ Wo,
    const float* __restrict__ x,
    unsigned short* __restrict__ wqkvT, unsigned short* __restrict__ woT,
    unsigned short* __restrict__ x_bf)
{
  const int bid = blockIdx.x;
  const int tid = threadIdx.x;
  if (bid < 256) {
    __shared__ unsigned short lds[64][65];
    const int z = bid >> 6, rest = bid & 63;
    const int k0 = (rest >> 3) * 64, n0 = (rest & 7) * 64;
    const float* W; unsigned short* T;
    if (z == 0)      { W = Wq; T = wqkvT; }
    else if (z == 1) { W = Wk; T = wqkvT + 262144; }
    else if (z == 2) { W = Wv; T = wqkvT + 524288; }
    else             { W = Wo; T = woT; }
    const int xx = tid & 63, yy = tid >> 6;
#pragma unroll
    for (int i = 0; i < 16; ++i) {
      const int row = yy * 16 + i;
      lds[row][xx] = f2bf(W[(size_t)(k0 + row) * 512 + n0 + xx]);
    }
    __syncthreads();
#pragma unroll
    for (int i = 0; i < 16; ++i) {
      const int nr = yy * 16 + i;
      T[(size_t)(n0 + nr) * 512 + k0 + xx] = lds[xx][nr];
    }
  } else {
    const int i = (bid - 256) * 256 + tid;
    const float4 a = ((const float4*)x)[i * 2];
    const float4 b = ((const float4*)x)[i * 2 + 1];
    ushortx8 o;
    o[0] = f2bf(a.x); o[1] = f2bf(a.y); o[2] = f2bf(a.z); o[3] = f2bf(a.w);
    o[4] = f2bf(b.x); o[5] = f2bf(b.y); o[6] = f2bf(b.z); o[7] = f2bf(b.w);
    *(ushortx8*)(x_bf + (size_t)i * 8) = o;
  }
}

// ---------------------------------------------------------------------------
// 128x128-tile bf16 GEMM for QKV projection. A = x_bf, B = wqkvT [1536][512].
// grid (64, 12); by selects output: 0-3 Q, 4-7 K, 8-11 V.
// V epilogue transposes the 128x128 tile through LDS so the [nbh][dv][t]
// stores are coalesced 16B chunks (was: 2B scatter, the R7 bottleneck).
// ---------------------------------------------------------------------------
__global__ __launch_bounds__(256) void gemm_qkv(
    const unsigned short* __restrict__ Xb,
    const unsigned short* __restrict__ BT,
    const float* __restrict__ bq, const float* __restrict__ bk,
    const float* __restrict__ bv,
    unsigned short* __restrict__ Qo, unsigned short* __restrict__ Ko,
    unsigned short* __restrict__ Vo)
{
  __shared__ __align__(16) unsigned short sbuf[18432];   // lA|lB, reused for transpose
  auto lA = (unsigned short (*)[72])sbuf;                // [128][72]
  auto lB = (unsigned short (*)[72])(sbuf + 9216);       // [128][72]
  const int tid  = threadIdx.x;
  const int wv   = tid >> 6, lane = tid & 63;
  const int quad = lane >> 4, l16 = lane & 15;
  const int wm = wv >> 1, wn = wv & 1;
  const int m0  = blockIdx.x * 128;
  const int n0g = blockIdx.y * 128;
  const int sel = n0g >> 9;                      // 0=Q,1=K,2=V
  const float* bias = (sel == 0) ? bq : (sel == 1) ? bk : bv;
  const float scale = (sel == 0) ? QSCALE : 1.0f;
  unsigned short* outp = (sel == 0) ? Qo : (sel == 1) ? Ko : Vo;

  floatx4 acc[4][4] = {};
  const int srow = tid >> 1, sc0 = (tid & 1) * 32;

  for (int kc = 0; kc < 512; kc += 64) {
    __syncthreads();
    const unsigned short* as = Xb + (size_t)(m0 + srow) * 512 + kc + sc0;
    const unsigned short* bs = BT + (size_t)(n0g + srow) * 512 + kc + sc0;
#pragma unroll
    for (int j = 0; j < 4; ++j) {
      *(bf16x8*)&lA[srow][sc0 + j * 8] = *(const bf16x8*)(as + j * 8);
      *(bf16x8*)&lB[srow][sc0 + j * 8] = *(const bf16x8*)(bs + j * 8);
    }
    __syncthreads();
    bf16x8 af[4][2];
#pragma unroll
    for (int ti = 0; ti < 4; ++ti) {
      af[ti][0] = *(const bf16x8*)&lA[wm * 64 + ti * 16 + l16][quad * 8];
      af[ti][1] = *(const bf16x8*)&lA[wm * 64 + ti * 16 + l16][32 + quad * 8];
    }
#pragma unroll
    for (int ni = 0; ni < 4; ++ni) {
      bf16x8 b0 = *(const bf16x8*)&lB[wn * 64 + ni * 16 + l16][quad * 8];
      bf16x8 b1 = *(const bf16x8*)&lB[wn * 64 + ni * 16 + l16][32 + quad * 8];
#pragma unroll
      for (int ti = 0; ti < 4; ++ti) {
        acc[ti][ni] = __builtin_amdgcn_mfma_f32_16x16x32_bf16(af[ti][0], b0, acc[ti][ni], 0, 0, 0);
        acc[ti][ni] = __builtin_amdgcn_mfma_f32_16x16x32_bf16(af[ti][1], b1, acc[ti][ni], 0, 0, 0);
      }
    }
  }

  if (sel != 2) {
    // Q/K: direct stores ([nbh][t][64]; 32B segments per quad -- fine)
#pragma unroll
    for (int ni = 0; ni < 4; ++ni) {
      const int n = (n0g & 511) + wn * 64 + ni * 16 + l16;
      const float bvv = bias[n];
      const int hh = n >> 6, dk = n & 63;
#pragma unroll
      for (int ti = 0; ti < 4; ++ti) {
        const int mb = m0 + wm * 64 + ti * 16 + quad * 4;
#pragma unroll
        for (int r = 0; r < 4; ++r) {
          const int m = mb + r;
          const int nb = m >> 9, t = m & 511;
          outp[((size_t)(nb * 8 + hh) * 512 + t) * 64 + dk] =
              f2bf((acc[ti][ni][r] + bvv) * scale);
        }
      }
    }
  } else {
    // V: transpose tile through LDS -> coalesced [nbh][dv][t] stores.
    __syncthreads();                       // all waves done reading lA/lB
    auto tb = (unsigned short (*)[136])sbuf;   // [128 dv][136] (stride 16B-mult)
#pragma unroll
    for (int ni = 0; ni < 4; ++ni) {
      const int n = (n0g & 511) + wn * 64 + ni * 16 + l16;
      const float bvv = bias[n];
      const int drow = wn * 64 + ni * 16 + l16;        // dv-local
#pragma unroll
      for (int ti = 0; ti < 4; ++ti) {
        const int tcol = wm * 64 + ti * 16 + quad * 4; // t-local (mult of 4)
        shortx4 pk;
        pk[0] = (short)f2bf(acc[ti][ni][0] + bvv);
        pk[1] = (short)f2bf(acc[ti][ni][1] + bvv);
        pk[2] = (short)f2bf(acc[ti][ni][2] + bvv);
        pk[3] = (short)f2bf(acc[ti][ni][3] + bvv);
        *(shortx4*)&tb[drow][tcol] = pk;               // b64, conflict-free
      }
    }
    __syncthreads();
    const int drow = tid >> 1, th = tid & 1;
    const int n = (n0g & 511) + drow;
    const int hh = n >> 6, dk = n & 63;
    const int nb = m0 >> 9, tbase = (m0 & 511) + th * 64;
    unsigned short* gdst = outp + ((size_t)(nb * 8 + hh) * 64 + dk) * 512 + tbase;
#pragma unroll
    for (int j = 0; j < 8; ++j)
      *(ushortx8*)(gdst + j * 8) = *(const ushortx8*)&tb[drow][th * 64 + j * 8];
  }
}

// ---------------------------------------------------------------------------
// 128x128-tile output projection with fused c-group reduce:
// A = ctx2[0] + ctx2[1] (added during staging), B = woT; tmp bf16 [8192][512].
// ---------------------------------------------------------------------------
__global__ __launch_bounds__(256) void gemm_out(
    const unsigned short* __restrict__ C0, const unsigned short* __restrict__ C1,
    const unsigned short* __restrict__ BT, unsigned short* __restrict__ Cout)
{
  __shared__ __align__(16) unsigned short lA[128][72];
  __shared__ __align__(16) unsigned short lB[128][72];
  const int tid  = threadIdx.x;
  const int wv   = tid >> 6, lane = tid & 63;
  const int quad = lane >> 4, l16 = lane & 15;
  const int wm = wv >> 1, wn = wv & 1;
  const int m0 = blockIdx.x * 128, n0 = blockIdx.y * 128;

  floatx4 acc[4][4] = {};
  const int srow = tid >> 1, sc0 = (tid & 1) * 32;

  for (int kc = 0; kc < 512; kc += 64) {
    __syncthreads();
    const size_t aoff = (size_t)(m0 + srow) * 512 + kc + sc0;
    const unsigned short* bs = BT + (size_t)(n0 + srow) * 512 + kc + sc0;
#pragma unroll
    for (int j = 0; j < 4; ++j) {
      ushortx8 a0 = *(const ushortx8*)(C0 + aoff + j * 8);
      ushortx8 a1 = *(const ushortx8*)(C1 + aoff + j * 8);
      ushortx8 o;
#pragma unroll
      for (int e = 0; e < 8; ++e) o[e] = f2bf(bf2f(a0[e]) + bf2f(a1[e]));
      *(ushortx8*)&lA[srow][sc0 + j * 8] = o;
      *(bf16x8*)&lB[srow][sc0 + j * 8] = *(const bf16x8*)(bs + j * 8);
    }
    __syncthreads();
    bf16x8 af[4][2];
#pragma unroll
    for (int ti = 0; ti < 4; ++ti) {
      af[ti][0] = *(const bf16x8*)&lA[wm * 64 + ti * 16 + l16][quad * 8];
      af[ti][1] = *(const bf16x8*)&lA[wm * 64 + ti * 16 + l16][32 + quad * 8];
    }
#pragma unroll
    for (int ni = 0; ni < 4; ++ni) {
      bf16x8 b0 = *(const bf16x8*)&lB[wn * 64 + ni * 16 + l16][quad * 8];
      bf16x8 b1 = *(const bf16x8*)&lB[wn * 64 + ni * 16 + l16][32 + quad * 8];
#pragma unroll
      for (int ti = 0; ti < 4; ++ti) {
        acc[ti][ni] = __builtin_amdgcn_mfma_f32_16x16x32_bf16(af[ti][0], b0, acc[ti][ni], 0, 0, 0);
        acc[ti][ni] = __builtin_amdgcn_mfma_f32_16x16x32_bf16(af[ti][1], b1, acc[ti][ni], 0, 0, 0);
      }
    }
  }

#pragma unroll
  for (int ni = 0; ni < 4; ++ni) {
    const int n = n0 + wn * 64 + ni * 16 + l16;
#pragma unroll
    for (int ti = 0; ti < 4; ++ti) {
      const int mb = m0 + wm * 64 + ti * 16 + quad * 4;
#pragma unroll
      for (int r = 0; r < 4; ++r)
        Cout[(size_t)(mb + r) * 512 + n] = f2bf(acc[ti][ni][r]);
    }
  }
}

// ---------------------------------------------------------------------------
// Flash attention v4 (R7 verbatim, proven 63-65 us): 2 key-vars per block
// (grid 1024). S^T = K·Q^T via 32x32x16 with C pre-init SHIFT2, Q pre-scaled
// QSCALE -> P = exp2(sacc). P passes from S^T acc directly into PV A-operand
// (zero LDS for P). 4 waves x 32 q-rows; double-buffer; 1 barrier/iter.
// Normalized partials -> CTX2[cg].
// ---------------------------------------------------------------------------
__global__ __launch_bounds__(256) void flash_kernel(
    const unsigned short* __restrict__ Q,    // [128][512][64] (pre-scaled)
    const unsigned short* __restrict__ K,    // [128][512][64]
    const unsigned short* __restrict__ VT,   // [128][64][512]
    unsigned short* __restrict__ CTX2)       // [2][8192][512]
{
  __shared__ __align__(16) unsigned short lK[2][64][72];
  __shared__ __align__(16) unsigned short lV[2][64][68];
  const int tid  = threadIdx.x;
  const int wv   = tid >> 6, lane = tid & 63;
  const int l32  = lane & 31, u = lane >> 5;

  const int lin  = blockIdx.x;                  // 0..1023
  const int xcd  = lin & 7, slot = lin >> 3;
  const int tile = slot & 3;
  const int nbh  = xcd * 16 + ((slot >> 2) & 15);
  const int cg   = slot >> 6;
  const int t0   = tile * 128;
  const int h = nbh & 7, nb = nbh >> 3, b = nb & 3;

  const unsigned short* qbase = Q + ((size_t)nbh * 512 + (t0 + wv * 32 + l32)) * 64;
  bf16x8 qf[4];
#pragma unroll
  for (int c16 = 0; c16 < 4; ++c16)
    qf[c16] = *(const bf16x8*)(qbase + c16 * 16 + u * 8);

  const int srow = tid >> 2, sc0 = (tid & 3) * 16;
  const unsigned short *kptr, *vptr;
  auto setptr = [&](int it) {
    const int c = cg * 2 + (it >> 3), s0 = (it & 7) * 64;
    const size_t kvbh = (size_t)((c * 4 + b) * 8 + h);
    kptr = K  + kvbh * (512 * 64) + (size_t)(s0 + srow) * 64 + sc0;
    vptr = VT + kvbh * (64 * 512) + (size_t)srow * 512 + s0 + sc0;
  };
  bf16x8 rk0, rk1, rv0, rv1;
  auto loadregs = [&]() {
    rk0 = *(const bf16x8*)kptr; rk1 = *(const bf16x8*)(kptr + 8);
    rv0 = *(const bf16x8*)vptr; rv1 = *(const bf16x8*)(vptr + 8);
  };
  auto writebuf = [&](int p) {
    *(bf16x8*)&lK[p][srow][sc0]     = rk0;
    *(bf16x8*)&lK[p][srow][sc0 + 8] = rk1;
    union { bf16x8 v8; bf16x4 v4[2]; } c0, c1;
    c0.v8 = rv0; c1.v8 = rv1;
    *(bf16x4*)&lV[p][srow][sc0]      = c0.v4[0];
    *(bf16x4*)&lV[p][srow][sc0 + 4]  = c0.v4[1];
    *(bf16x4*)&lV[p][srow][sc0 + 8]  = c1.v4[0];
    *(bf16x4*)&lV[p][srow][sc0 + 12] = c1.v4[1];
  };

  setptr(0); loadregs();
  writebuf(0);
  setptr(1); loadregs();
  __syncthreads();

  floatx16 ofin0 = {}, ofin1 = {};
  floatx16 oc0, oc1;
  float lacc;

  for (int it = 0; it < 16; ++it) {
    const int cur = it & 1;
    const int st = it & 7;
    if (st == 0) { oc0 = floatx16{}; oc1 = floatx16{}; lacc = 0.f; }

    if (it < 15) writebuf(cur ^ 1);
    if (it < 14) { setptr(it + 2); loadregs(); }

    floatx16 sacc0, sacc1;
#pragma unroll
    for (int r = 0; r < 16; ++r) { sacc0[r] = SHIFT2; sacc1[r] = SHIFT2; }
#pragma unroll
    for (int c16 = 0; c16 < 4; ++c16) {
      bf16x8 ak0 = *(const bf16x8*)&lK[cur][l32][c16 * 16 + u * 8];
      bf16x8 ak1 = *(const bf16x8*)&lK[cur][32 + l32][c16 * 16 + u * 8];
      sacc0 = __builtin_amdgcn_mfma_f32_32x32x16_bf16(ak0, qf[c16], sacc0, 0, 0, 0);
      sacc1 = __builtin_amdgcn_mfma_f32_32x32x16_bf16(ak1, qf[c16], sacc1, 0, 0, 0);
    }

#pragma unroll
    for (int sb = 0; sb < 2; ++sb) {
      const floatx16& sa = sb ? sacc1 : sacc0;
#pragma unroll
      for (int c8 = 0; c8 < 4; ++c8) {
        float e0 = __builtin_amdgcn_exp2f(sa[4 * c8 + 0]);
        float e1 = __builtin_amdgcn_exp2f(sa[4 * c8 + 1]);
        float e2 = __builtin_amdgcn_exp2f(sa[4 * c8 + 2]);
        float e3 = __builtin_amdgcn_exp2f(sa[4 * c8 + 3]);
        lacc += (e0 + e1) + (e2 + e3);
        shortx4 pf;
        pf[0] = (short)f2bf(e0); pf[1] = (short)f2bf(e1);
        pf[2] = (short)f2bf(e2); pf[3] = (short)f2bf(e3);
        const int sloc = sb * 32 + c8 * 8 + u * 4;
        shortx4 vf0 = *(const shortx4*)&lV[cur][l32][sloc];
        shortx4 vf1 = *(const shortx4*)&lV[cur][32 + l32][sloc];
        oc0 = __builtin_amdgcn_mfma_f32_32x32x8bf16_1k(pf, vf0, oc0, 0, 0, 0);
        oc1 = __builtin_amdgcn_mfma_f32_32x32x8bf16_1k(pf, vf1, oc1, 0, 0, 0);
      }
    }

    if (st == 7) {
      float s = lacc;
      s += __shfl_xor(s, 32);
      const float inv = 1.0f / s;
#pragma unroll
      for (int r = 0; r < 16; ++r) {
        const int trow = (r & 3) + 8 * (r >> 2) + 4 * u;
        const float invr = __shfl(inv, trow);
        ofin0[r] += oc0[r] * invr;
        ofin1[r] += oc1[r] * invr;
      }
    }
    __syncthreads();
  }

  unsigned short* outp = CTX2 + (size_t)cg * (8192 * 512);
  const int mbase = nb * 512 + t0 + wv * 32;
#pragma unroll
  for (int r = 0; r < 16; ++r) {
    const int trow = (r & 3) + 8 * (r >> 2) + 4 * u;
    const size_t rowoff = (size_t)(mbase + trow) * 512 + h * 64;
    outp[rowoff + l32]      = f2bf(ofin0[r]);
    outp[rowoff + 32 + l32] = f2bf(ofin1[r]);
  }
}

// ---------------------------------------------------------------------------
// Residual + LayerNorm (fp32 out), one wave per row; tmp is bf16.
// ---------------------------------------------------------------------------
__global__ __launch_bounds__(256) void ln_kernel(
    const float* __restrict__ x, const unsigned short* __restrict__ tmpb,
    const float* __restrict__ bo, const float* __restrict__ gamma,
    const float* __restrict__ beta, float* __restrict__ out)
{
  const int wv   = threadIdx.x >> 6, lane = threadIdx.x & 63;
  const int row  = blockIdx.x * 4 + wv;
  const int col  = lane * 8;
  const size_t base = (size_t)row * 512 + col;
  const float4 x0 = *(const float4*)(x + base);
  const float4 x1 = *(const float4*)(x + base + 4);
  const ushortx8 t8 = *(const ushortx8*)(tmpb + base);
  const float4 b0 = *(const float4*)(bo + col);
  const float4 b1 = *(const float4*)(bo + col + 4);
  float r[8];
  r[0] = x0.x + 0.25f * bf2f(t8[0]) + b0.x;  r[1] = x0.y + 0.25f * bf2f(t8[1]) + b0.y;
  r[2] = x0.z + 0.25f * bf2f(t8[2]) + b0.z;  r[3] = x0.w + 0.25f * bf2f(t8[3]) + b0.w;
  r[4] = x1.x + 0.25f * bf2f(t8[4]) + b1.x;  r[5] = x1.y + 0.25f * bf2f(t8[5]) + b1.y;
  r[6] = x1.z + 0.25f * bf2f(t8[6]) + b1.z;  r[7] = x1.w + 0.25f * bf2f(t8[7]) + b1.w;
  float s = 0.f, sq = 0.f;
#pragma unroll
  for (int j = 0; j < 8; ++j) { s += r[j]; sq += r[j] * r[j]; }
#pragma unroll
  for (int off = 1; off < 64; off <<= 1) {
    s  += __shfl_xor(s, off);
    sq += __shfl_xor(sq, off);
  }
  const float mu  = s * (1.0f / 512.0f);
  const float var = sq * (1.0f / 512.0f) - mu * mu;
  const float inv = rsqrtf(var + 1e-5f);
  const float4 g0 = *(const float4*)(gamma + col);
  const float4 g1 = *(const float4*)(gamma + col + 4);
  const float4 be0 = *(const float4*)(beta + col);
  const float4 be1 = *(const float4*)(beta + col + 4);
  float4 o0, o1;
  o0.x = (r[0] - mu) * inv * g0.x + be0.x;  o0.y = (r[1] - mu) * inv * g0.y + be0.y;
  o0.z = (r[2] - mu) * inv * g0.z + be0.z;  o0.w = (r[3] - mu) * inv * g0.w + be0.w;
  o1.x = (r[4] - mu) * inv * g1.x + be1.x;  o1.y = (r[5] - mu) * inv * g1.y + be1.y;
  o1.z = (r[6] - mu) * inv * g1.z + be1.z;  o1.w = (r[7] - mu) * inv * g1.w + be1.w;
  *(float4*)(out + base)     = o0;
  *(float4*)(out + base + 4) = o1;
}

// ---------------------------------------------------------------------------
extern "C" void kernel_launch(void* const* d_in, const int* in_sizes, int n_in,
                              void* d_out, int out_size, void* d_ws, size_t ws_size,
                              hipStream_t stream) {
  const float* x     = (const float*)d_in[0];
  const float* Wq    = (const float*)d_in[1];
  const float* bq    = (const float*)d_in[2];
  const float* Wk    = (const float*)d_in[3];
  const float* bk    = (const float*)d_in[4];
  const float* Wv    = (const float*)d_in[5];
  const float* bv    = (const float*)d_in[6];
  const float* Wo    = (const float*)d_in[7];
  const float* bo    = (const float*)d_in[8];
  const float* gamma = (const float*)d_in[9];
  const float* beta  = (const float*)d_in[10];
  float* out = (float*)d_out;

  // Workspace (42 MB):
  //   [0,  8M)  q_bf   (qkv->flash)          | tmp bf16 [0,8M) after flash
  //   [8, 16M)  k_bf   (qkv->flash)
  //   [16,24M)  vt_bf  (qkv->flash)
  //   [24,32M)  x_bf   (prep->qkv)           | ctx2[0] (flash->gemm_out)
  //   [32,40M)                                 ctx2[1]
  //   [40,41.5M) wqkvT [1536][512]; [41.5,42M) woT
  char* w = (char*)d_ws;
  unsigned short* q_bf  = (unsigned short*)(w);
  unsigned short* k_bf  = (unsigned short*)(w + (size_t)8  * 1024 * 1024);
  unsigned short* vt_bf = (unsigned short*)(w + (size_t)16 * 1024 * 1024);
  unsigned short* x_bf  = (unsigned short*)(w + (size_t)24 * 1024 * 1024);
  unsigned short* ctx2  = (unsigned short*)(w + (size_t)24 * 1024 * 1024);
  unsigned short* wqkvT = (unsigned short*)(w + (size_t)40 * 1024 * 1024);
  unsigned short* woT   = wqkvT + 786432;
  unsigned short* tmpb  = (unsigned short*)(w);   // over q_bf (dead post-flash)

  prep<<<2304, 256, 0, stream>>>(Wq, Wk, Wv, Wo, x, wqkvT, woT, x_bf);
  gemm_qkv<<<dim3(64, 12), 256, 0, stream>>>(x_bf, wqkvT, bq, bk, bv,
                                             q_bf, k_bf, vt_bf);
  flash_kernel<<<1024, 256, 0, stream>>>(q_bf, k_bf, vt_bf, ctx2);
  gemm_out<<<dim3(64, 4), 256, 0, stream>>>(ctx2, ctx2 + (size_t)8192 * 512,
                                            woT, tmpb);
  ln_kernel<<<2048, 256, 0, stream>>>(x, tmpb, bo, gamma, beta, out);
}